// Round 2
// baseline (1360.118 us; speedup 1.0000x reference)
//
#include <hip/hip_runtime.h>
#include <math.h>

#define LEAKY 0.2f
#define HDIM 64
#define NREP 8

// ws layout (floats): [0, nrep*4N) acc replicas (float4/node: x,y,z,cnt),
//                     [nrep*4N, +8) consts
//   consts[0] = C_edge (collapsed edge-MLP linear coefficient)
//   consts[1] = flag: any bp1[k] != 0  (forces general slow path)

__device__ __forceinline__ unsigned xcc_id() {
    unsigned v;
    asm volatile("s_getreg_b32 %0, hwreg(HW_REG_XCC_ID)" : "=s"(v));
    return v & (NREP - 1u);
}

__global__ void precompute_kernel(const float* __restrict__ Wp1,
                                  const float* __restrict__ bp1,
                                  const float* __restrict__ Wp2,
                                  float* __restrict__ consts) {
    int k = threadIdx.x;  // 64 threads == HDIM == one wave
    float w1 = Wp1[k];
    float slope = (w1 >= 0.f) ? 1.f : LEAKY;
    float c = Wp2[k] * w1 * slope;
    float bnz = (bp1[k] != 0.f) ? 1.f : 0.f;
    #pragma unroll
    for (int off = 32; off > 0; off >>= 1) {
        c += __shfl_down(c, off, 64);
        bnz += __shfl_down(bnz, off, 64);
    }
    if (k == 0) { consts[0] = c; consts[1] = bnz; }
}

__global__ void edge_kernel(const float* __restrict__ x, const int* __restrict__ ei,
                            const float* __restrict__ Wp1, const float* __restrict__ bp1,
                            const float* __restrict__ Wp2,
                            const float* __restrict__ consts,
                            float* __restrict__ acc,
                            int E, int N, int nrep) {
    __shared__ float sW1[HDIM], sb1[HDIM], sW2[HDIM];
    const float C = consts[0];
    const bool slow = (consts[1] != 0.f);
    if (slow) {
        for (int k = threadIdx.x; k < HDIM; k += blockDim.x) {
            sW1[k] = Wp1[k]; sb1[k] = bp1[k]; sW2[k] = Wp2[k];
        }
        __syncthreads();
    }
    int e = blockIdx.x * blockDim.x + threadIdx.x;
    if (e >= E) return;
    int r = ei[e];
    int c = ei[E + e];
    float dx = x[3*r]     - x[3*c];
    float dy = x[3*r + 1] - x[3*c + 1];
    float dz = x[3*r + 2] - x[3*c + 2];
    float rad = sqrtf(dx*dx + dy*dy + dz*dz);
    float eo;
    if (!slow) {
        // bp1 == 0 and rad >= 0: leaky_relu(rad*Wp1[k]) = rad*Wp1[k]*slope_k,
        // so the whole MLP is tanh(C * rad).
        eo = tanhf(C * rad);
    } else {
        float a = 0.f;
        #pragma unroll
        for (int k = 0; k < HDIM; k++) {
            float h = fmaf(rad, sW1[k], sb1[k]);
            h = (h > 0.f) ? h : LEAKY * h;
            a = fmaf(sW2[k], h, a);
        }
        eo = tanhf(a);
    }
    float mx = dx * eo, my = dy * eo, mz = dz * eo;
    if (nrep > 1) {
        // XCD-local replica: only blocks on XCD i touch replica i, so a
        // non-bypassing (workgroup-scope) atomic executed in the local TCC
        // is atomic for all writers of this replica. Kernel-end release
        // writes back L2 so the node kernel sees the result.
        float* base = acc + (((size_t)xcc_id() * N + (size_t)r) << 2);
        __hip_atomic_fetch_add(base + 0, mx,  __ATOMIC_RELAXED, __HIP_MEMORY_SCOPE_WORKGROUP);
        __hip_atomic_fetch_add(base + 1, my,  __ATOMIC_RELAXED, __HIP_MEMORY_SCOPE_WORKGROUP);
        __hip_atomic_fetch_add(base + 2, mz,  __ATOMIC_RELAXED, __HIP_MEMORY_SCOPE_WORKGROUP);
        __hip_atomic_fetch_add(base + 3, 1.f, __ATOMIC_RELAXED, __HIP_MEMORY_SCOPE_WORKGROUP);
    } else {
        float* base = acc + ((size_t)r << 2);
        atomicAdd(base + 0, mx);
        atomicAdd(base + 1, my);
        atomicAdd(base + 2, mz);
        atomicAdd(base + 3, 1.f);
    }
}

__global__ void node_kernel(const float* __restrict__ x, const float* __restrict__ vel_norm,
                            const float* __restrict__ vel,
                            const float* __restrict__ W1, const float* __restrict__ b1,
                            const float* __restrict__ W2, const float* __restrict__ b2,
                            const float* __restrict__ acc,
                            float* __restrict__ out, int N, int nrep) {
    __shared__ float sW1[HDIM], sb1[HDIM], sW2[HDIM];
    for (int k = threadIdx.x; k < HDIM; k += blockDim.x) {
        sW1[k] = W1[k]; sb1[k] = b1[k]; sW2[k] = W2[k];
    }
    __syncthreads();
    int i = blockIdx.x * blockDim.x + threadIdx.x;
    if (i >= N) return;
    float sx = 0.f, sy = 0.f, sz = 0.f, sc = 0.f;
    const float4* a4 = (const float4*)acc;
    for (int rdx = 0; rdx < nrep; rdx++) {
        float4 v = a4[(size_t)rdx * N + i];
        sx += v.x; sy += v.y; sz += v.z; sc += v.w;
    }
    float vn = vel_norm[i];
    float a = b2[0];
    #pragma unroll
    for (int k = 0; k < HDIM; k++) {
        float h = fmaf(vn, sW1[k], sb1[k]);
        h = (h > 0.f) ? h : LEAKY * h;
        a = fmaf(sW2[k], h, a);
    }
    float inv = 1.0f / fmaxf(sc, 1.0f);
    out[3*i]     = x[3*i]     + sx * inv + vel[3*i]     * a;
    out[3*i + 1] = x[3*i + 1] + sy * inv + vel[3*i + 1] * a;
    out[3*i + 2] = x[3*i + 2] + sz * inv + vel[3*i + 2] * a;
}

extern "C" void kernel_launch(void* const* d_in, const int* in_sizes, int n_in,
                              void* d_out, int out_size, void* d_ws, size_t ws_size,
                              hipStream_t stream) {
    const float* x        = (const float*)d_in[0];
    const float* vel_norm = (const float*)d_in[1];
    const float* vel      = (const float*)d_in[2];
    const int*   ei       = (const int*)  d_in[3];
    const float* W1       = (const float*)d_in[4];
    const float* b1       = (const float*)d_in[5];
    const float* W2       = (const float*)d_in[6];
    const float* b2       = (const float*)d_in[7];
    const float* Wp1      = (const float*)d_in[8];
    const float* bp1      = (const float*)d_in[9];
    const float* Wp2      = (const float*)d_in[10];

    const int N = in_sizes[0] / 3;
    const int E = in_sizes[3] / 2;

    int nrep = NREP;
    size_t need = ((size_t)nrep * N * 4 + 8) * sizeof(float);
    if (ws_size < need) { nrep = 1; need = ((size_t)N * 4 + 8) * sizeof(float); }

    float* acc    = (float*)d_ws;                         // nrep*4N floats
    float* consts = (float*)d_ws + (size_t)nrep * N * 4;  // 8 floats

    hipMemsetAsync(d_ws, 0, need, stream);

    precompute_kernel<<<1, 64, 0, stream>>>(Wp1, bp1, Wp2, consts);
    edge_kernel<<<(E + 255) / 256, 256, 0, stream>>>(x, ei, Wp1, bp1, Wp2, consts,
                                                     acc, E, N, nrep);
    node_kernel<<<(N + 255) / 256, 256, 0, stream>>>(x, vel_norm, vel, W1, b1, W2, b2,
                                                     acc, (float*)d_out, N, nrep);
}

// Round 3
// 354.938 us; speedup vs baseline: 3.8320x; 3.8320x over previous
//
#include <hip/hip_runtime.h>
#include <hip/hip_fp16.h>
#include <math.h>

#define LEAKY 0.2f
#define HDIM 64
#define EPB 4096            // edges per bin block
#define TPB1 256
#define PERT (EPB / TPB1)   // 16 edges per thread
#define RANGE 2048          // nodes per bucket
#define RSH 11
#define KMAX 64
#define NSLICE 12

// record: bits [0,11) lid, [11,27) f16 mx, [27,43) f16 my, [43,59) f16 mz

__global__ void precompute_kernel(const float* __restrict__ Wp1,
                                  const float* __restrict__ bp1,
                                  const float* __restrict__ Wp2,
                                  float* __restrict__ consts) {
    int k = threadIdx.x;  // 64 threads == HDIM == one wave
    float w1 = Wp1[k];
    float slope = (w1 >= 0.f) ? 1.f : LEAKY;
    float c = Wp2[k] * w1 * slope;
    float bnz = (bp1[k] != 0.f) ? 1.f : 0.f;
    #pragma unroll
    for (int off = 32; off > 0; off >>= 1) {
        c += __shfl_down(c, off, 64);
        bnz += __shfl_down(bnz, off, 64);
    }
    if (k == 0) { consts[0] = c; consts[1] = bnz; }
}

__device__ __forceinline__ float edge_eo(float rad, float C, bool slow,
                                         const float* sW1, const float* sb1,
                                         const float* sW2) {
    if (!slow) return tanhf(C * rad);  // bp1==0, rad>=0: MLP collapses to linear
    float a = 0.f;
    #pragma unroll
    for (int k = 0; k < HDIM; k++) {
        float h = fmaf(rad, sW1[k], sb1[k]);
        h = (h > 0.f) ? h : LEAKY * h;
        a = fmaf(sW2[k], h, a);
    }
    return tanhf(a);
}

__global__ __launch_bounds__(TPB1) void bin_kernel(
        const float* __restrict__ x, const int* __restrict__ ei,
        const float* __restrict__ Wp1, const float* __restrict__ bp1,
        const float* __restrict__ Wp2, const float* __restrict__ consts,
        uint2* __restrict__ recs, unsigned* __restrict__ offs, int E, int K) {
    __shared__ uint2 stage[EPB];
    __shared__ unsigned hist[KMAX];
    __shared__ unsigned scanv[KMAX + 1];
    __shared__ float sW1[HDIM], sb1[HDIM], sW2[HDIM];
    const float C = consts[0];
    const bool slow = (consts[1] != 0.f);
    if (slow) {
        for (int k = threadIdx.x; k < HDIM; k += TPB1) {
            sW1[k] = Wp1[k]; sb1[k] = bp1[k]; sW2[k] = Wp2[k];
        }
    }
    for (int k = threadIdx.x; k < K; k += TPB1) hist[k] = 0;
    __syncthreads();

    int base = blockIdx.x * EPB;
    uint2 rc[PERT];
    unsigned bk[PERT];
    #pragma unroll
    for (int i = 0; i < PERT; i++) {
        int e = base + i * TPB1 + threadIdx.x;
        bk[i] = 0xFFFFFFFFu;
        if (e < E) {
            int r = ei[e];
            int c = ei[E + e];
            float dx = x[3*r]     - x[3*c];
            float dy = x[3*r + 1] - x[3*c + 1];
            float dz = x[3*r + 2] - x[3*c + 2];
            float rad = sqrtf(dx*dx + dy*dy + dz*dz);
            float eo = edge_eo(rad, C, slow, sW1, sb1, sW2);
            unsigned hx = __half_as_ushort(__float2half(dx * eo));
            unsigned hy = __half_as_ushort(__float2half(dy * eo));
            unsigned hz = __half_as_ushort(__float2half(dz * eo));
            unsigned b   = (unsigned)r >> RSH;
            unsigned lid = (unsigned)r & (RANGE - 1);
            unsigned long long u = (unsigned long long)lid
                                 | ((unsigned long long)hx << 11)
                                 | ((unsigned long long)hy << 27)
                                 | ((unsigned long long)hz << 43);
            rc[i] = make_uint2((unsigned)u, (unsigned)(u >> 32));
            bk[i] = b;
            atomicAdd(&hist[b], 1u);
        }
    }
    __syncthreads();
    if (threadIdx.x == 0) {
        unsigned acc = 0;
        for (int k = 0; k < K; k++) { scanv[k] = acc; acc += hist[k]; }
        scanv[K] = acc;
    }
    __syncthreads();
    for (int k = threadIdx.x; k < K; k += TPB1) hist[k] = scanv[k];  // running cursors
    __syncthreads();
    #pragma unroll
    for (int i = 0; i < PERT; i++) {
        if (bk[i] != 0xFFFFFFFFu) {
            unsigned slot = atomicAdd(&hist[bk[i]], 1u);
            stage[slot] = rc[i];
        }
    }
    __syncthreads();
    unsigned total = scanv[K];
    for (unsigned j = threadIdx.x; j < total; j += TPB1)
        recs[(size_t)base + j] = stage[j];
    for (int k = threadIdx.x; k <= K; k += TPB1)
        offs[(size_t)blockIdx.x * (K + 1) + k] = scanv[k];
}

__global__ __launch_bounds__(256) void reduce_kernel(
        const uint2* __restrict__ recs, const unsigned* __restrict__ offs,
        float4* __restrict__ slices, int nblk1, int N, int K) {
    __shared__ float acc[RANGE * 4];
    int b = blockIdx.x / NSLICE;
    int s = blockIdx.x % NSLICE;
    for (int i = threadIdx.x; i < RANGE * 4; i += 256) acc[i] = 0.f;
    __syncthreads();
    for (int r = s; r < nblk1; r += NSLICE) {
        unsigned st = offs[(size_t)r * (K + 1) + b];
        unsigned en = offs[(size_t)r * (K + 1) + b + 1];
        size_t rb = (size_t)r * EPB;
        for (unsigned j = st + threadIdx.x; j < en; j += 256) {
            uint2 rcv = recs[rb + j];
            unsigned long long u = ((unsigned long long)rcv.y << 32) | rcv.x;
            unsigned lid = (unsigned)(u & (RANGE - 1));
            float mx = __half2float(__ushort_as_half((unsigned short)((u >> 11) & 0xFFFF)));
            float my = __half2float(__ushort_as_half((unsigned short)((u >> 27) & 0xFFFF)));
            float mz = __half2float(__ushort_as_half((unsigned short)((u >> 43) & 0xFFFF)));
            atomicAdd(&acc[lid * 4 + 0], mx);
            atomicAdd(&acc[lid * 4 + 1], my);
            atomicAdd(&acc[lid * 4 + 2], mz);
            atomicAdd(&acc[lid * 4 + 3], 1.f);
        }
    }
    __syncthreads();
    int nbase = b * RANGE;
    for (int i = threadIdx.x; i < RANGE; i += 256) {
        int node = nbase + i;
        if (node < N)
            slices[(size_t)s * N + node] =
                make_float4(acc[i*4], acc[i*4+1], acc[i*4+2], acc[i*4+3]);
    }
}

__global__ void node_kernel(const float* __restrict__ x, const float* __restrict__ vel_norm,
                            const float* __restrict__ vel,
                            const float* __restrict__ W1, const float* __restrict__ b1,
                            const float* __restrict__ W2, const float* __restrict__ b2,
                            const float4* __restrict__ slices,
                            float* __restrict__ out, int N, int S) {
    __shared__ float sW1[HDIM], sb1[HDIM], sW2[HDIM];
    for (int k = threadIdx.x; k < HDIM; k += blockDim.x) {
        sW1[k] = W1[k]; sb1[k] = b1[k]; sW2[k] = W2[k];
    }
    __syncthreads();
    int i = blockIdx.x * blockDim.x + threadIdx.x;
    if (i >= N) return;
    float sx = 0.f, sy = 0.f, sz = 0.f, sc = 0.f;
    for (int s = 0; s < S; s++) {
        float4 v = slices[(size_t)s * N + i];
        sx += v.x; sy += v.y; sz += v.z; sc += v.w;
    }
    float vn = vel_norm[i];
    float a = b2[0];
    #pragma unroll
    for (int k = 0; k < HDIM; k++) {
        float h = fmaf(vn, sW1[k], sb1[k]);
        h = (h > 0.f) ? h : LEAKY * h;
        a = fmaf(sW2[k], h, a);
    }
    float inv = 1.0f / fmaxf(sc, 1.0f);
    out[3*i]     = x[3*i]     + sx * inv + vel[3*i]     * a;
    out[3*i + 1] = x[3*i + 1] + sy * inv + vel[3*i + 1] * a;
    out[3*i + 2] = x[3*i + 2] + sz * inv + vel[3*i + 2] * a;
}

// fallback: plain device-scope atomics (round-1 behavior)
__global__ void edge_atomic_kernel(const float* __restrict__ x, const int* __restrict__ ei,
                                   const float* __restrict__ Wp1, const float* __restrict__ bp1,
                                   const float* __restrict__ Wp2, const float* __restrict__ consts,
                                   float* __restrict__ acc, int E) {
    __shared__ float sW1[HDIM], sb1[HDIM], sW2[HDIM];
    const float C = consts[0];
    const bool slow = (consts[1] != 0.f);
    if (slow) {
        for (int k = threadIdx.x; k < HDIM; k += blockDim.x) {
            sW1[k] = Wp1[k]; sb1[k] = bp1[k]; sW2[k] = Wp2[k];
        }
        __syncthreads();
    }
    int e = blockIdx.x * blockDim.x + threadIdx.x;
    if (e >= E) return;
    int r = ei[e];
    int c = ei[E + e];
    float dx = x[3*r] - x[3*c];
    float dy = x[3*r+1] - x[3*c+1];
    float dz = x[3*r+2] - x[3*c+2];
    float rad = sqrtf(dx*dx + dy*dy + dz*dz);
    float eo = edge_eo(rad, C, slow, sW1, sb1, sW2);
    float* basep = acc + ((size_t)r << 2);
    atomicAdd(basep + 0, dx * eo);
    atomicAdd(basep + 1, dy * eo);
    atomicAdd(basep + 2, dz * eo);
    atomicAdd(basep + 3, 1.f);
}

extern "C" void kernel_launch(void* const* d_in, const int* in_sizes, int n_in,
                              void* d_out, int out_size, void* d_ws, size_t ws_size,
                              hipStream_t stream) {
    const float* x        = (const float*)d_in[0];
    const float* vel_norm = (const float*)d_in[1];
    const float* vel      = (const float*)d_in[2];
    const int*   ei       = (const int*)  d_in[3];
    const float* W1       = (const float*)d_in[4];
    const float* b1       = (const float*)d_in[5];
    const float* W2       = (const float*)d_in[6];
    const float* b2       = (const float*)d_in[7];
    const float* Wp1      = (const float*)d_in[8];
    const float* bp1      = (const float*)d_in[9];
    const float* Wp2      = (const float*)d_in[10];

    const int N = in_sizes[0] / 3;
    const int E = in_sizes[3] / 2;
    const int K = (N + RANGE - 1) / RANGE;
    const int nblk1 = (E + EPB - 1) / EPB;

    size_t off_slices = 0;
    size_t off_recs   = off_slices + (size_t)NSLICE * N * sizeof(float4);
    size_t off_offs   = off_recs + (size_t)nblk1 * EPB * sizeof(uint2);
    size_t off_consts = (off_offs + (size_t)nblk1 * (K + 1) * sizeof(unsigned) + 15) & ~(size_t)15;
    size_t need = off_consts + 32;

    if (K <= KMAX && ws_size >= need) {
        float4*   slices = (float4*)  ((char*)d_ws + off_slices);
        uint2*    recs   = (uint2*)   ((char*)d_ws + off_recs);
        unsigned* offs   = (unsigned*)((char*)d_ws + off_offs);
        float*    consts = (float*)   ((char*)d_ws + off_consts);
        precompute_kernel<<<1, 64, 0, stream>>>(Wp1, bp1, Wp2, consts);
        bin_kernel<<<nblk1, TPB1, 0, stream>>>(x, ei, Wp1, bp1, Wp2, consts,
                                               recs, offs, E, K);
        reduce_kernel<<<K * NSLICE, 256, 0, stream>>>(recs, offs, slices, nblk1, N, K);
        node_kernel<<<(N + 255) / 256, 256, 0, stream>>>(x, vel_norm, vel, W1, b1, W2, b2,
                                                         slices, (float*)d_out, N, NSLICE);
    } else {
        // fallback: device-scope atomics
        float* acc    = (float*)d_ws;                    // N float4
        float* consts = (float*)((char*)d_ws + (size_t)N * sizeof(float4));
        hipMemsetAsync(d_ws, 0, (size_t)N * sizeof(float4) + 32, stream);
        precompute_kernel<<<1, 64, 0, stream>>>(Wp1, bp1, Wp2, consts);
        edge_atomic_kernel<<<(E + 255) / 256, 256, 0, stream>>>(x, ei, Wp1, bp1, Wp2,
                                                                consts, acc, E);
        node_kernel<<<(N + 255) / 256, 256, 0, stream>>>(x, vel_norm, vel, W1, b1, W2, b2,
                                                         (const float4*)acc, (float*)d_out, N, 1);
    }
}